// Round 2
// baseline (12553.226 us; speedup 1.0000x reference)
//
#include <hip/hip_runtime.h>
#include <stdint.h>

#define HDIM 96
#define G3   288
#define TLEN 239
#define BB   16
#define NBLK 256    // 4096 / 16
#define NTHR 768    // 12 waves: 6 gh + 6 gi

typedef _Float16 f16;
typedef f16  f16x8 __attribute__((ext_vector_type(8)));
typedef f16  f16x4 __attribute__((ext_vector_type(4)));
typedef float f32x4 __attribute__((ext_vector_type(4)));

__device__ __forceinline__ float sigm(float x)  { return 1.f / (1.f + __expf(-x)); }
__device__ __forceinline__ float tanh_(float x) { return 1.f - 2.f / (1.f + __expf(2.f * x)); }

// seq = d_out, [B][H][T] fp32. Read as x for layer>0, written in place.
template<bool HAS_X>
__global__ __launch_bounds__(NTHR, 3)
void gru_layer(float* seq,
               const float* __restrict__ zin, const float* __restrict__ cin,
               const float* __restrict__ fc1w, const float* __restrict__ fc1b,
               const float* __restrict__ wih, const float* __restrict__ whh,
               const float* __restrict__ bih, const float* __restrict__ bhh,
               int layer)
{
  __shared__ f16   h_plane[2][16][104];   // double-buffered h (f16), padded
  __shared__ float gi_buf[16][300];       // gi pre-activations (fp32), padded
  __shared__ float xcat[4][512];          // fc1 input rows (4 rows per block)
  __shared__ float fc1o[4][384];          // fc1 outputs (post-LeakyReLU)

  const int tid = threadIdx.x;
  const int wv  = tid >> 6;
  const int ln  = tid & 63;
  const int r0  = blockIdx.x * BB;
  const int g   = ln >> 4;
  const int lm  = ln & 15;

  // ---- fc1: h0 comes from h.reshape(L,B,H) of the [B,4H] fc1 output:
  //      h0[l][b][h] = fc1_out[l*1024 + b/4][(b%4)*96 + h]
  // This block needs fc1 rows base_in..base_in+3, ALL 384 output features.
  const int base_in = layer * 1024 + (r0 >> 2);
  for (int i = tid; i < 4 * 512; i += NTHR) {
    int q = i >> 9, k = i & 511;
    xcat[q][k] = (k < 256) ? zin[(base_in + q) * 256 + k]
                           : cin[(base_in + q) * 256 + (k - 256)];
  }
  __syncthreads();
  for (int of = wv * 32; of < wv * 32 + 32; ++of) {
    float wreg[8];
    #pragma unroll
    for (int i = 0; i < 8; ++i) wreg[i] = fc1w[of * 512 + ln + 64 * i];
    float s[4];
    #pragma unroll
    for (int q = 0; q < 4; ++q) {
      float a = 0.f;
      #pragma unroll
      for (int i = 0; i < 8; ++i) a += wreg[i] * xcat[q][ln + 64 * i];
      s[q] = a;
    }
    #pragma unroll
    for (int off = 32; off; off >>= 1)
      #pragma unroll
      for (int q = 0; q < 4; ++q) s[q] += __shfl_down(s[q], off);
    if (ln == 0) {
      float b = fc1b[of];
      #pragma unroll
      for (int q = 0; q < 4; ++q) {
        float v = s[q] + b;
        fc1o[q][of] = (v >= 0.f) ? v : 0.2f * v;   // LeakyReLU(0.2)
      }
    }
  }
  __syncthreads();

  const bool is_gh = (wv < 6);
  const int  wg    = is_gh ? wv : wv - 6;
  const int  col   = wg * 16 + lm;          // 0..95 gate column within each gate block

  // ---------------- weight fragments in VGPRs (B-operand) ----------------
  // B[k][n] = w[gate = nt*96+col][k]; shorts 0-3: k=kt*32+4g+j, 4-7: k=kt*32+16+4g+j
  f16x8 wf[3][3];
  if (is_gh || HAS_X) {
    const float* wmat = is_gh ? whh : wih;
    #pragma unroll
    for (int nt = 0; nt < 3; ++nt)
      #pragma unroll
      for (int kt = 0; kt < 3; ++kt) {
        const float* src = wmat + (nt * 96 + col) * 96 + kt * 32 + 4 * g;
        f16x8 f;
        #pragma unroll
        for (int j = 0; j < 4; ++j) { f[j] = (f16)src[j]; f[4 + j] = (f16)src[16 + j]; }
        wf[nt][kt] = f;
      }
  }

  float bir = 0, biz = 0, bin_ = 0, bhr = 0, bhz = 0, bhn = 0;
  float hprev[4] = {0, 0, 0, 0};
  uint32_t obase[4] = {0, 0, 0, 0};
  if (is_gh) {
    bir = bih[col]; biz = bih[96 + col]; bin_ = bih[192 + col];
    bhr = bhh[col]; bhz = bhh[96 + col]; bhn = bhh[192 + col];
    #pragma unroll
    for (int j = 0; j < 4; ++j) {
      // block-local row i = 4g+j  ->  fc1o[i>>2][(i&3)*96 + col] = fc1o[g][j*96+col]
      float h0v = fc1o[g][j * 96 + col];
      hprev[j] = h0v;
      h_plane[0][4 * g + j][col] = (f16)h0v;
      obase[j] = ((uint32_t)(r0 + 4 * g + j) * 96 + col) * 239;
    }
  }

  // x gather pointers (gi waves): A[m][k], m = lm, k = kt*32+16*hh+4g (+j via stride 239)
  const float* xptr[6];
  float xc[6][4];
  if (!is_gh && HAS_X) {
    #pragma unroll
    for (int kt = 0; kt < 3; ++kt)
      #pragma unroll
      for (int hh = 0; hh < 2; ++hh) {
        int k = kt * 32 + 16 * hh + 4 * g;
        xptr[kt * 2 + hh] = seq + ((size_t)(r0 + lm) * 96 + k) * 239;
      }
    #pragma unroll
    for (int f = 0; f < 6; ++f)
      #pragma unroll
      for (int j = 0; j < 4; ++j) xc[f][j] = xptr[f][j * 239];   // t = 0
  }
  __syncthreads();

  // ---------------- time loop ----------------
  float hist[4][8];
  for (int t0 = 0; t0 < TLEN; t0 += 8) {
    const int nsteps = (TLEN - t0 < 8) ? (TLEN - t0) : 8;
    #pragma unroll
    for (int s = 0; s < 8; ++s) {
      if (s < nsteps) {
        const int t = t0 + s;
        const int buf = t & 1;
        const f32x4 z4 = {0.f, 0.f, 0.f, 0.f};
        f32x4 acc[3] = {z4, z4, z4};

        // ---- phase A: matmuls ----
        if (is_gh) {
          #pragma unroll
          for (int kt = 0; kt < 3; ++kt) {
            f16x4 lo = *(const f16x4*)&h_plane[buf][lm][kt * 32 + 4 * g];
            f16x4 hi = *(const f16x4*)&h_plane[buf][lm][kt * 32 + 16 + 4 * g];
            f16x8 a;
            #pragma unroll
            for (int j = 0; j < 4; ++j) { a[j] = lo[j]; a[4 + j] = hi[j]; }
            #pragma unroll
            for (int nt = 0; nt < 3; ++nt)
              acc[nt] = __builtin_amdgcn_mfma_f32_16x16x32_f16(a, wf[nt][kt], acc[nt], 0, 0, 0);
          }
        } else if (HAS_X) {
          #pragma unroll
          for (int kt = 0; kt < 3; ++kt) {
            f16x8 a;
            #pragma unroll
            for (int j = 0; j < 4; ++j) { a[j] = (f16)xc[2 * kt][j]; a[4 + j] = (f16)xc[2 * kt + 1][j]; }
            #pragma unroll
            for (int nt = 0; nt < 3; ++nt)
              acc[nt] = __builtin_amdgcn_mfma_f32_16x16x32_f16(a, wf[nt][kt], acc[nt], 0, 0, 0);
          }
          #pragma unroll
          for (int nt = 0; nt < 3; ++nt)
            #pragma unroll
            for (int reg = 0; reg < 4; ++reg)
              gi_buf[4 * g + reg][nt * 96 + col] = acc[nt][reg];
          if (t + 1 < TLEN) {     // prefetch next step's x
            #pragma unroll
            for (int f = 0; f < 6; ++f)
              #pragma unroll
              for (int j = 0; j < 4; ++j) xc[f][j] = xptr[f][(t + 1) + j * 239];
          }
        }
        __syncthreads();

        // ---- phase B: gates + h update (gh waves) ----
        if (is_gh) {
          #pragma unroll
          for (int reg = 0; reg < 4; ++reg) {
            float gr = acc[0][reg] + bhr;
            float gz = acc[1][reg] + bhz;
            float gn = acc[2][reg] + bhn;
            float ir = bir, iz = biz, in_ = bin_;
            if (HAS_X) {
              ir  += gi_buf[4 * g + reg][col];
              iz  += gi_buf[4 * g + reg][96 + col];
              in_ += gi_buf[4 * g + reg][192 + col];
            }
            float r  = sigm(ir + gr);
            float zg = sigm(iz + gz);
            float n  = tanh_(in_ + r * gn);
            float hn = (1.f - zg) * n + zg * hprev[reg];
            hprev[reg] = hn;
            hist[reg][s] = hn;
            h_plane[buf ^ 1][4 * g + reg][col] = (f16)hn;
          }
        }
        __syncthreads();
      }
    }
    // flush 8-step history: t-contiguous 32B runs per (row,col)
    if (is_gh) {
      #pragma unroll
      for (int reg = 0; reg < 4; ++reg)
        #pragma unroll
        for (int q = 0; q < 8; ++q)
          if (q < nsteps) seq[obase[reg] + (uint32_t)(t0 + q)] = hist[reg][q];
    }
  }
}

extern "C" void kernel_launch(void* const* d_in, const int* in_sizes, int n_in,
                              void* d_out, int out_size, void* d_ws, size_t ws_size,
                              hipStream_t stream) {
  const float* zin  = (const float*)d_in[0];
  const float* cin  = (const float*)d_in[1];
  const float* fc1w = (const float*)d_in[2];
  const float* fc1b = (const float*)d_in[3];
  const float* wih  = (const float*)d_in[4];
  const float* whh  = (const float*)d_in[5];
  const float* bih  = (const float*)d_in[6];
  const float* bhh  = (const float*)d_in[7];
  float* seq = (float*)d_out;
  (void)d_ws; (void)ws_size; (void)in_sizes; (void)n_in; (void)out_size;

  dim3 grid(NBLK), blk(NTHR);
  gru_layer<false><<<grid, blk, 0, stream>>>(seq, zin, cin, fc1w, fc1b,
                                             wih, whh, bih, bhh, 0);
  for (int l = 1; l < 4; ++l)
    gru_layer<true><<<grid, blk, 0, stream>>>(seq, zin, cin, fc1w, fc1b,
                                              wih + l * G3 * HDIM, whh + l * G3 * HDIM,
                                              bih + l * G3, bhh + l * G3, l);
}